// Round 5
// baseline (94.644 us; speedup 1.0000x reference)
//
#include <hip/hip_runtime.h>
#include <math.h>

#define D 8192
#define B 8
#define E 131072
#define HID 256
#define TDIM 128
#define MAXDEG 64

// ws float-index layout
#define OFF_XT 0
#define OFF_DD 65536
#define OFF_UU 131072
#define OFF_Y0 196608
#define OFF_Y1 262144
#define OFF_G  327680
#define OFF_SC 329728
// ws int-index layout ((int*)ws)
#define IOFF_CNT  329760
#define IOFF_EDGE 346144   // int2[2*8192*64] => 2,097,152 ints

// blocks 0..63  : xT transpose + zero bucket counters
// blocks 64..71 : per-batch time-embedding MLP -> g = map_b + t_out
// block  72     : 9 collapsed scalars sc[j*3+k] = sum_i W1[0,i,k]*W2[i,0,j]
__global__ __launch_bounds__(1024) void k_front(
        const float* __restrict__ x, const float* __restrict__ t,
        const float* __restrict__ W1, const float* __restrict__ W2,
        const float* __restrict__ t_w1, const float* __restrict__ t_b1,
        const float* __restrict__ t_w2, const float* __restrict__ t_b2,
        const float* __restrict__ map_b, float* __restrict__ ws)
{
    const int blk = blockIdx.x, tid = threadIdx.x;
    if (blk < 64) {
        int idx = blk * 1024 + tid;               // 0..65535
        ws[OFF_XT + idx] = x[(idx & 7) * D + (idx >> 3)];
        if (idx < 16384) ((int*)ws)[IOFF_CNT + idx] = 0;
        return;
    }
    if (blk < 72) {
        const int b = blk - 64;
        __shared__ float emb[TDIM];
        __shared__ float h1[HID];
        __shared__ float part[4][HID];
        float tb = t[b];
        if (tid < TDIM) {
            int j = tid & 63;
            float freq = expf(-0.14391156831212787f * (float)j); // ln(10000)/64
            float a = tb * freq;
            emb[tid] = (tid < 64) ? cosf(a) : sinf(a);
        }
        __syncthreads();
        const int j = tid & 255, ic = tid >> 8;   // ic in 0..3
        float z = 0.f;
        #pragma unroll 8
        for (int i = ic * 32; i < ic * 32 + 32; i++) z += emb[i] * t_w1[i * HID + j];
        part[ic][j] = z;
        __syncthreads();
        if (tid < HID) {
            float zz = t_b1[tid] + part[0][tid] + part[1][tid] + part[2][tid] + part[3][tid];
            h1[tid] = zz / (1.f + expf(-zz));
        }
        __syncthreads();
        float z2 = 0.f;
        #pragma unroll 8
        for (int i = ic * 64; i < ic * 64 + 64; i++) z2 += h1[i] * t_w2[i * HID + j];
        part[ic][j] = z2;
        __syncthreads();
        if (tid < HID) {
            float zz = t_b2[tid] + part[0][tid] + part[1][tid] + part[2][tid] + part[3][tid];
            (ws + OFF_G)[b * HID + tid] = map_b[tid] + zz;
        }
        return;
    }
    // block 72: 9 scalars via per-wave shuffle reduction (waves 0..8)
    {
        int w = tid >> 6, lane = tid & 63;
        if (w < 9) {
            int jj = w / 3, k = w % 3;
            float acc = 0.f;
            #pragma unroll
            for (int q = 0; q < 4; q++) {
                int i = lane + 64 * q;
                acc += W1[i * 3 + k] * W2[i * 3 + jj];
            }
            #pragma unroll
            for (int off = 32; off > 0; off >>= 1) acc += __shfl_down(acc, off, 64);
            if (lane == 0) (ws + OFF_SC)[jj * 3 + k] = acc;
        }
    }
}

// Build padded per-row edge buckets: edges[bucket*64 + slot] = (col, val)
__global__ void k_fill(const int* __restrict__ ldi, const float* __restrict__ ldv,
                       const int* __restrict__ lui, const float* __restrict__ luv,
                       float* __restrict__ ws)
{
    int t = blockIdx.x * 256 + threadIdx.x;       // 0 .. 2E-1
    int m = t >> 17;                              // E = 2^17
    int e = t & (E - 1);
    const int* idx = m ? lui : ldi;
    const float* val = m ? luv : ldv;
    int row = idx[e];
    int col = idx[E + e];
    float v = val[e];
    int bucket = m * D + row;
    int* cnt = (int*)ws + IOFF_CNT;
    int2* edges = (int2*)((int*)ws + IOFF_EDGE);
    int slot = atomicAdd(&cnt[bucket], 1);
    edges[bucket * MAXDEG + slot] = make_int2(col, __float_as_int(v));
}

// dd[r,b] / uu[r,b] = sum_edges v * xT[col,b]   (gather, no atomics)
__global__ void k_spmv1(float* __restrict__ ws)
{
    int t = blockIdx.x * 256 + threadIdx.x;       // 0 .. 131071
    int m = t >> 16, r = (t >> 3) & (D - 1), b = t & 7;
    int bucket = m * D + r;
    const int* cnt = (const int*)ws + IOFF_CNT;
    const int2* edges = (const int2*)((const int*)ws + IOFF_EDGE);
    int deg = cnt[bucket];
    const int2* ep = edges + bucket * MAXDEG;
    float acc = 0.f;
    #pragma unroll 2
    for (int p = 0; p < deg; p++) {
        int2 ed = ep[p];
        acc += __int_as_float(ed.y) * ws[OFF_XT + ed.x * 8 + b];
    }
    ws[(m ? OFF_UU : OFF_DD) + r * 8 + b] = acc;
}

// m=0: y0[r,b] = a0 x + a1 d + a2 u + sum_d v*(sc3 x + sc4 d + sc5 u)[col,b]
// m=1: y1[r,b] =                      sum_u v*(sc6 x + sc7 d + sc8 u)[col,b]
__global__ void k_spmv2(float* __restrict__ ws)
{
    int t = blockIdx.x * 256 + threadIdx.x;       // 0 .. 131071
    int m = t >> 16, r = (t >> 3) & (D - 1), b = t & 7;
    int bucket = m * D + r;
    const float* sc = ws + OFF_SC;
    const int* cnt = (const int*)ws + IOFF_CNT;
    const int2* edges = (const int2*)((const int*)ws + IOFF_EDGE);
    int deg = cnt[bucket];
    const int2* ep = edges + bucket * MAXDEG;
    float c0, c1, c2;
    if (m == 0) { c0 = sc[3]; c1 = sc[4]; c2 = sc[5]; }
    else        { c0 = sc[6]; c1 = sc[7]; c2 = sc[8]; }
    float acc = 0.f;
    #pragma unroll 2
    for (int p = 0; p < deg; p++) {
        int2 ed = ep[p];
        int ci = ed.x * 8 + b;
        float h = c0 * ws[OFF_XT + ci] + c1 * ws[OFF_DD + ci] + c2 * ws[OFF_UU + ci];
        acc += __int_as_float(ed.y) * h;
    }
    int i = r * 8 + b;
    if (m == 0) {
        acc += sc[0] * ws[OFF_XT + i] + sc[1] * ws[OFF_DD + i] + sc[2] * ws[OFF_UU + i];
        ws[OFF_Y0 + i] = acc;
    } else {
        ws[OFF_Y1 + i] = acc;
    }
}

// g[b,j] += sum_n (y0+y1)[n,b] * map_w[n,j]   (64 blocks x 128 rows each)
__global__ void k_map(const float* __restrict__ map_w, float* __restrict__ ws)
{
    __shared__ float yl[128 * 8];
    int blk = blockIdx.x, tid = threadIdx.x;
    float* g = ws + OFF_G;
    int base = blk * 128 * 8;
    for (int i = tid; i < 1024; i += 256)
        yl[i] = ws[OFF_Y0 + base + i] + ws[OFF_Y1 + base + i];
    __syncthreads();
    float acc[8] = {0.f, 0.f, 0.f, 0.f, 0.f, 0.f, 0.f, 0.f};
    int nbase = blk * 128;
    #pragma unroll 4
    for (int r = 0; r < 128; r++) {
        float w = map_w[(nbase + r) * HID + tid];
        #pragma unroll
        for (int b = 0; b < 8; b++) acc[b] += yl[r * 8 + b] * w;
    }
    #pragma unroll
    for (int b = 0; b < 8; b++) atomicAdd(&g[b * HID + tid], acc[b]);
}

// fused: s = silu(g @ o_w1 + o_b1) (recomputed per block), out = s @ o_w2 + o_b2
// 32 blocks x 256 threads, each block owns a 256-wide n-chunk; single writer.
__global__ void k_out(const float* __restrict__ o_w1, const float* __restrict__ o_b1,
                      const float* __restrict__ o_w2, const float* __restrict__ o_b2,
                      const float* __restrict__ ws, float* __restrict__ out)
{
    __shared__ float gs[B * HID];
    __shared__ float ssl[B * HID];
    int blk = blockIdx.x, tid = threadIdx.x;
    const float* g = ws + OFF_G;
    for (int i = tid; i < B * HID; i += 256) gs[i] = g[i];
    __syncthreads();
    // stage B: s[b][tid] for all b
    {
        float z[8];
        float bias = o_b1[tid];
        #pragma unroll
        for (int b = 0; b < 8; b++) z[b] = bias;
        for (int i = 0; i < HID; i++) {
            float w = o_w1[i * HID + tid];
            #pragma unroll
            for (int b = 0; b < 8; b++) z[b] += gs[b * HID + i] * w;
        }
        #pragma unroll
        for (int b = 0; b < 8; b++)
            ssl[b * HID + tid] = z[b] / (1.f + expf(-z[b]));
    }
    __syncthreads();
    // stage C: out[b][n] for this block's n-chunk
    int n = blk * 256 + tid;
    float acc[8];
    float bias2 = o_b2[n];
    #pragma unroll
    for (int b = 0; b < 8; b++) acc[b] = bias2;
    #pragma unroll 4
    for (int j = 0; j < HID; j++) {
        float w = o_w2[j * D + n];
        #pragma unroll
        for (int b = 0; b < 8; b++) acc[b] += ssl[b * HID + j] * w;
    }
    #pragma unroll
    for (int b = 0; b < 8; b++) out[b * D + n] = acc[b];
}

extern "C" void kernel_launch(void* const* d_in, const int* in_sizes, int n_in,
                              void* d_out, int out_size, void* d_ws, size_t ws_size,
                              hipStream_t stream)
{
    const float* x     = (const float*)d_in[0];
    const float* t     = (const float*)d_in[1];
    const int*   ldi   = (const int*)  d_in[2];
    const float* ldv   = (const float*)d_in[3];
    const int*   lui   = (const int*)  d_in[4];
    const float* luv   = (const float*)d_in[5];
    const float* W1    = (const float*)d_in[6];
    const float* W2    = (const float*)d_in[7];
    const float* t_w1  = (const float*)d_in[8];
    const float* t_b1  = (const float*)d_in[9];
    const float* t_w2  = (const float*)d_in[10];
    const float* t_b2  = (const float*)d_in[11];
    const float* map_w = (const float*)d_in[12];
    const float* map_b = (const float*)d_in[13];
    const float* o_w1  = (const float*)d_in[14];
    const float* o_b1  = (const float*)d_in[15];
    const float* o_w2  = (const float*)d_in[16];
    const float* o_b2  = (const float*)d_in[17];
    float* out = (float*)d_out;
    float* ws  = (float*)d_ws;

    k_front<<<73, 1024, 0, stream>>>(x, t, W1, W2, t_w1, t_b1, t_w2, t_b2, map_b, ws);
    k_fill<<<2 * E / 256, 256, 0, stream>>>(ldi, ldv, lui, luv, ws);
    k_spmv1<<<512, 256, 0, stream>>>(ws);
    k_spmv2<<<512, 256, 0, stream>>>(ws);
    k_map<<<64, 256, 0, stream>>>(map_w, ws);
    k_out<<<32, 256, 0, stream>>>(o_w1, o_b1, o_w2, o_b2, ws, out);
}

// Round 7
// 68.209 us; speedup vs baseline: 1.3875x; 1.3875x over previous
//
#include <hip/hip_runtime.h>
#include <math.h>

#define D 8192
#define B 8
#define E 131072
#define HID 256
#define TDIM 128
#define MAXDEG 64

// ws float-index layout
#define OFF_XT 0
#define OFF_DD 65536
#define OFF_UU 131072
#define OFF_Y0 196608
#define OFF_Y1 262144
#define OFF_G  327680
#define OFF_S  329728
#define OFF_SC 331776
// ws int-index layout ((int*)ws)
#define IOFF_CNT  331808   // 16384 ints -> ends at 348191
#define IOFF_EDGE 348192   // int2[2*8192*64] = 2,097,152 ints

// blocks 0..63  : xT transpose + zero bucket counters + out = o_b2
// blocks 64..71 : per-batch time-embedding MLP -> g = map_b + t_out
// block  72     : 9 collapsed scalars sc[j*3+k] = sum_i W1[0,i,k]*W2[i,0,j]
__global__ __launch_bounds__(1024) void k_front(
        const float* __restrict__ x, const float* __restrict__ t,
        const float* __restrict__ W1, const float* __restrict__ W2,
        const float* __restrict__ t_w1, const float* __restrict__ t_b1,
        const float* __restrict__ t_w2, const float* __restrict__ t_b2,
        const float* __restrict__ map_b, const float* __restrict__ o_b2,
        float* __restrict__ ws, float* __restrict__ out)
{
    const int blk = blockIdx.x, tid = threadIdx.x;
    if (blk < 64) {
        int idx = blk * 1024 + tid;               // 0..65535
        ws[OFF_XT + idx] = x[(idx & 7) * D + (idx >> 3)];
        if (idx < 16384) ((int*)ws)[IOFF_CNT + idx] = 0;
        out[idx] = o_b2[idx & (D - 1)];           // idx = b*D + n
        return;
    }
    if (blk < 72) {
        const int b = blk - 64;
        __shared__ float emb[TDIM];
        __shared__ float h1[HID];
        __shared__ float part[4][HID];
        float tb = t[b];
        if (tid < TDIM) {
            int j = tid & 63;
            float freq = expf(-0.14391156831212787f * (float)j); // ln(10000)/64
            float a = tb * freq;
            emb[tid] = (tid < 64) ? cosf(a) : sinf(a);
        }
        __syncthreads();
        const int j = tid & 255, ic = tid >> 8;   // ic in 0..3
        float z = 0.f;
        #pragma unroll 8
        for (int i = ic * 32; i < ic * 32 + 32; i++) z += emb[i] * t_w1[i * HID + j];
        part[ic][j] = z;
        __syncthreads();
        if (tid < HID) {
            float zz = t_b1[tid] + part[0][tid] + part[1][tid] + part[2][tid] + part[3][tid];
            h1[tid] = zz / (1.f + expf(-zz));
        }
        __syncthreads();
        float z2 = 0.f;
        #pragma unroll 8
        for (int i = ic * 64; i < ic * 64 + 64; i++) z2 += h1[i] * t_w2[i * HID + j];
        part[ic][j] = z2;
        __syncthreads();
        if (tid < HID) {
            float zz = t_b2[tid] + part[0][tid] + part[1][tid] + part[2][tid] + part[3][tid];
            (ws + OFF_G)[b * HID + tid] = map_b[tid] + zz;
        }
        return;
    }
    // block 72: 9 scalars via per-wave shuffle reduction (waves 0..8)
    {
        int w = tid >> 6, lane = tid & 63;
        if (w < 9) {
            int jj = w / 3, k = w % 3;
            float acc = 0.f;
            #pragma unroll
            for (int q = 0; q < 4; q++) {
                int i = lane + 64 * q;
                acc += W1[i * 3 + k] * W2[i * 3 + jj];
            }
            #pragma unroll
            for (int off = 32; off > 0; off >>= 1) acc += __shfl_down(acc, off, 64);
            if (lane == 0) (ws + OFF_SC)[jj * 3 + k] = acc;
        }
    }
}

// Build padded per-row edge buckets: edges[bucket*64 + slot] = (col, val)
__global__ void k_fill(const int* __restrict__ ldi, const float* __restrict__ ldv,
                       const int* __restrict__ lui, const float* __restrict__ luv,
                       float* __restrict__ ws)
{
    int t = blockIdx.x * 256 + threadIdx.x;       // 0 .. 2E-1
    int m = t >> 17;                              // E = 2^17
    int e = t & (E - 1);
    const int* idx = m ? lui : ldi;
    const float* val = m ? luv : ldv;
    int row = idx[e];
    int col = idx[E + e];
    float v = val[e];
    int bucket = m * D + row;
    int* cnt = (int*)ws + IOFF_CNT;
    int2* edges = (int2*)((int*)ws + IOFF_EDGE);
    int slot = atomicAdd(&cnt[bucket], 1);
    edges[bucket * MAXDEG + slot] = make_int2(col, __float_as_int(v));
}

// dd[r,b] / uu[r,b] = sum_edges v * xT[col,b]   (gather, no atomics)
__global__ void k_spmv1(float* __restrict__ ws)
{
    int t = blockIdx.x * 256 + threadIdx.x;       // 0 .. 131071
    int m = t >> 16, r = (t >> 3) & (D - 1), b = t & 7;
    int bucket = m * D + r;
    const int* cnt = (const int*)ws + IOFF_CNT;
    const int2* edges = (const int2*)((const int*)ws + IOFF_EDGE);
    int deg = cnt[bucket];
    const int2* ep = edges + bucket * MAXDEG;
    float acc = 0.f;
    #pragma unroll 2
    for (int p = 0; p < deg; p++) {
        int2 ed = ep[p];
        acc += __int_as_float(ed.y) * ws[OFF_XT + ed.x * 8 + b];
    }
    ws[(m ? OFF_UU : OFF_DD) + r * 8 + b] = acc;
}

// m=0: y0[r,b] = a0 x + a1 d + a2 u + sum_d v*(sc3 x + sc4 d + sc5 u)[col,b]
// m=1: y1[r,b] =                      sum_u v*(sc6 x + sc7 d + sc8 u)[col,b]
__global__ void k_spmv2(float* __restrict__ ws)
{
    int t = blockIdx.x * 256 + threadIdx.x;       // 0 .. 131071
    int m = t >> 16, r = (t >> 3) & (D - 1), b = t & 7;
    int bucket = m * D + r;
    const float* sc = ws + OFF_SC;
    const int* cnt = (const int*)ws + IOFF_CNT;
    const int2* edges = (const int2*)((const int*)ws + IOFF_EDGE);
    int deg = cnt[bucket];
    const int2* ep = edges + bucket * MAXDEG;
    float c0, c1, c2;
    if (m == 0) { c0 = sc[3]; c1 = sc[4]; c2 = sc[5]; }
    else        { c0 = sc[6]; c1 = sc[7]; c2 = sc[8]; }
    float acc = 0.f;
    #pragma unroll 2
    for (int p = 0; p < deg; p++) {
        int2 ed = ep[p];
        int ci = ed.x * 8 + b;
        float h = c0 * ws[OFF_XT + ci] + c1 * ws[OFF_DD + ci] + c2 * ws[OFF_UU + ci];
        acc += __int_as_float(ed.y) * h;
    }
    int i = r * 8 + b;
    if (m == 0) {
        acc += sc[0] * ws[OFF_XT + i] + sc[1] * ws[OFF_DD + i] + sc[2] * ws[OFF_UU + i];
        ws[OFF_Y0 + i] = acc;
    } else {
        ws[OFF_Y1 + i] = acc;
    }
}

// g[b,j] += sum_n (y0+y1)[n,b] * map_w[n,j]   (64 blocks x 128 rows each)
__global__ void k_map(const float* __restrict__ map_w, float* __restrict__ ws)
{
    __shared__ float yl[128 * 8];
    int blk = blockIdx.x, tid = threadIdx.x;
    float* g = ws + OFF_G;
    int base = blk * 128 * 8;
    for (int i = tid; i < 1024; i += 256)
        yl[i] = ws[OFF_Y0 + base + i] + ws[OFF_Y1 + base + i];
    __syncthreads();
    float acc[8] = {0.f, 0.f, 0.f, 0.f, 0.f, 0.f, 0.f, 0.f};
    int nbase = blk * 128;
    #pragma unroll 4
    for (int r = 0; r < 128; r++) {
        float w = map_w[(nbase + r) * HID + tid];
        #pragma unroll
        for (int b = 0; b < 8; b++) acc[b] += yl[r * 8 + b] * w;
    }
    #pragma unroll
    for (int b = 0; b < 8; b++) atomicAdd(&g[b * HID + tid], acc[b]);
}

// s[b,j] = silu(sum_i g[b,i]*o_w1[i,j] + o_b1[j])  (8 blocks x 1024 thr, 4-way split)
__global__ __launch_bounds__(1024) void k_mlp(const float* __restrict__ o_w1,
                                              const float* __restrict__ o_b1,
                                              float* __restrict__ ws)
{
    __shared__ float gs[HID];
    __shared__ float part[4][HID];
    int b = blockIdx.x, tid = threadIdx.x;
    if (tid < HID) gs[tid] = (ws + OFF_G)[b * HID + tid];
    __syncthreads();
    int j = tid & 255, ic = tid >> 8;
    float z = 0.f;
    #pragma unroll 8
    for (int i = ic * 64; i < ic * 64 + 64; i++) z += gs[i] * o_w1[i * HID + j];
    part[ic][j] = z;
    __syncthreads();
    if (tid < HID) {
        float zz = o_b1[tid] + part[0][tid] + part[1][tid] + part[2][tid] + part[3][tid];
        (ws + OFF_S)[b * HID + tid] = zz / (1.f + expf(-zz));
    }
}

// out[b,n] += sum_j s[b,j]*o_w2[j,n]   (grid 32 n-chunks x 4 j-chunks, out pre-biased)
__global__ void k_out(const float* __restrict__ o_w2, const float* __restrict__ ws,
                      float* __restrict__ out)
{
    __shared__ float ssl[8 * 64];
    int nc = blockIdx.x, jc = blockIdx.y, tid = threadIdx.x;
    const float* s = ws + OFF_S;
    for (int i = tid; i < 512; i += 256) {
        int b = i >> 6, jj = i & 63;
        ssl[i] = s[b * HID + jc * 64 + jj];
    }
    __syncthreads();
    int n = nc * 256 + tid;
    float acc[8] = {0.f, 0.f, 0.f, 0.f, 0.f, 0.f, 0.f, 0.f};
    #pragma unroll 4
    for (int jj = 0; jj < 64; jj++) {
        int j = jc * 64 + jj;
        float w = o_w2[j * D + n];
        #pragma unroll
        for (int b = 0; b < 8; b++) acc[b] += ssl[b * 64 + jj] * w;
    }
    #pragma unroll
    for (int b = 0; b < 8; b++) atomicAdd(&out[b * D + n], acc[b]);
}

extern "C" void kernel_launch(void* const* d_in, const int* in_sizes, int n_in,
                              void* d_out, int out_size, void* d_ws, size_t ws_size,
                              hipStream_t stream)
{
    const float* x     = (const float*)d_in[0];
    const float* t     = (const float*)d_in[1];
    const int*   ldi   = (const int*)  d_in[2];
    const float* ldv   = (const float*)d_in[3];
    const int*   lui   = (const int*)  d_in[4];
    const float* luv   = (const float*)d_in[5];
    const float* W1    = (const float*)d_in[6];
    const float* W2    = (const float*)d_in[7];
    const float* t_w1  = (const float*)d_in[8];
    const float* t_b1  = (const float*)d_in[9];
    const float* t_w2  = (const float*)d_in[10];
    const float* t_b2  = (const float*)d_in[11];
    const float* map_w = (const float*)d_in[12];
    const float* map_b = (const float*)d_in[13];
    const float* o_w1  = (const float*)d_in[14];
    const float* o_b1  = (const float*)d_in[15];
    const float* o_w2  = (const float*)d_in[16];
    const float* o_b2  = (const float*)d_in[17];
    float* out = (float*)d_out;
    float* ws  = (float*)d_ws;

    k_front<<<73, 1024, 0, stream>>>(x, t, W1, W2, t_w1, t_b1, t_w2, t_b2,
                                     map_b, o_b2, ws, out);
    k_fill<<<2 * E / 256, 256, 0, stream>>>(ldi, ldv, lui, luv, ws);
    k_spmv1<<<512, 256, 0, stream>>>(ws);
    k_spmv2<<<512, 256, 0, stream>>>(ws);
    k_map<<<64, 256, 0, stream>>>(map_w, ws);
    k_mlp<<<8, 1024, 0, stream>>>(o_w1, o_b1, ws);
    k_out<<<dim3(32, 4), 256, 0, stream>>>(o_w2, ws, out);
}

// Round 8
// 66.805 us; speedup vs baseline: 1.4167x; 1.0210x over previous
//
#include <hip/hip_runtime.h>
#include <math.h>

#define D 8192
#define B 8
#define E 131072
#define HID 256
#define TDIM 128
#define MAXDEG 64

// ws float-index layout
#define OFF_XT 0
#define OFF_DD 65536
#define OFF_UU 131072
#define OFF_Y0 196608
#define OFF_Y1 262144
#define OFF_G  327680
#define OFF_S  329728
#define OFF_SC 331776
// ws int-index layout ((int*)ws)
#define IOFF_CNT  331808   // 16384 ints -> ends at 348191
#define IOFF_EDGE 348192   // int2[2*8192*64] = 2,097,152 ints

// blocks 0..63  : xT transpose + zero bucket counters + out = o_b2
// blocks 64..71 : per-batch time-embedding MLP -> g = map_b + t_out
// block  72     : 9 collapsed scalars sc[j*3+k] = sum_i W1[0,i,k]*W2[i,0,j]
__global__ __launch_bounds__(1024) void k_front(
        const float* __restrict__ x, const float* __restrict__ t,
        const float* __restrict__ W1, const float* __restrict__ W2,
        const float* __restrict__ t_w1, const float* __restrict__ t_b1,
        const float* __restrict__ t_w2, const float* __restrict__ t_b2,
        const float* __restrict__ map_b, const float* __restrict__ o_b2,
        float* __restrict__ ws, float* __restrict__ out)
{
    const int blk = blockIdx.x, tid = threadIdx.x;
    if (blk < 64) {
        int idx = blk * 1024 + tid;               // 0..65535
        ws[OFF_XT + idx] = x[(idx & 7) * D + (idx >> 3)];
        if (idx < 16384) ((int*)ws)[IOFF_CNT + idx] = 0;
        out[idx] = o_b2[idx & (D - 1)];           // idx = b*D + n
        return;
    }
    if (blk < 72) {
        const int b = blk - 64;
        __shared__ float emb[TDIM];
        __shared__ float h1[HID];
        __shared__ float part[4][HID];
        float tb = t[b];
        if (tid < TDIM) {
            int j = tid & 63;
            float freq = expf(-0.14391156831212787f * (float)j); // ln(10000)/64
            float a = tb * freq;
            emb[tid] = (tid < 64) ? cosf(a) : sinf(a);
        }
        __syncthreads();
        const int j = tid & 255, ic = tid >> 8;   // ic in 0..3
        float z = 0.f;
        #pragma unroll 8
        for (int i = ic * 32; i < ic * 32 + 32; i++) z += emb[i] * t_w1[i * HID + j];
        part[ic][j] = z;
        __syncthreads();
        if (tid < HID) {
            float zz = t_b1[tid] + part[0][tid] + part[1][tid] + part[2][tid] + part[3][tid];
            h1[tid] = zz / (1.f + expf(-zz));
        }
        __syncthreads();
        float z2 = 0.f;
        #pragma unroll 8
        for (int i = ic * 64; i < ic * 64 + 64; i++) z2 += h1[i] * t_w2[i * HID + j];
        part[ic][j] = z2;
        __syncthreads();
        if (tid < HID) {
            float zz = t_b2[tid] + part[0][tid] + part[1][tid] + part[2][tid] + part[3][tid];
            (ws + OFF_G)[b * HID + tid] = map_b[tid] + zz;
        }
        return;
    }
    // block 72: 9 scalars via per-wave shuffle reduction (waves 0..8)
    {
        int w = tid >> 6, lane = tid & 63;
        if (w < 9) {
            int jj = w / 3, k = w % 3;
            float acc = 0.f;
            #pragma unroll
            for (int q = 0; q < 4; q++) {
                int i = lane + 64 * q;
                acc += W1[i * 3 + k] * W2[i * 3 + jj];
            }
            #pragma unroll
            for (int off = 32; off > 0; off >>= 1) acc += __shfl_down(acc, off, 64);
            if (lane == 0) (ws + OFF_SC)[jj * 3 + k] = acc;
        }
    }
}

// Build padded per-row edge buckets: edges[bucket*64 + slot] = (col, val)
__global__ void k_fill(const int* __restrict__ ldi, const float* __restrict__ ldv,
                       const int* __restrict__ lui, const float* __restrict__ luv,
                       float* __restrict__ ws)
{
    int t = blockIdx.x * 256 + threadIdx.x;       // 0 .. 2E-1
    int m = t >> 17;                              // E = 2^17
    int e = t & (E - 1);
    const int* idx = m ? lui : ldi;
    const float* val = m ? luv : ldv;
    int row = idx[e];
    int col = idx[E + e];
    float v = val[e];
    int bucket = m * D + row;
    int* cnt = (int*)ws + IOFF_CNT;
    int2* edges = (int2*)((int*)ws + IOFF_EDGE);
    int slot = atomicAdd(&cnt[bucket], 1);
    edges[bucket * MAXDEG + slot] = make_int2(col, __float_as_int(v));
}

// wave-per-bucket gather SpMV: dd[r,b] / uu[r,b] = sum_edges v * xT[col,b]
// lane = slot*8 + b ; slots strided by 8 ; 3-step shfl_xor reduce over slots
__global__ void k_spmv1(float* __restrict__ ws)
{
    int wid = (blockIdx.x * 256 + threadIdx.x) >> 6;   // 0 .. 16383 (= bucket)
    int lane = threadIdx.x & 63;
    int m = wid >> 13, r = wid & (D - 1);
    const int* cnt = (const int*)ws + IOFF_CNT;
    const int2* edges = (const int2*)((const int*)ws + IOFF_EDGE);
    int deg = cnt[wid];
    const int2* ep = edges + wid * MAXDEG;
    int slot = lane >> 3, b = lane & 7;
    float acc = 0.f;
    for (int p = slot; p < deg; p += 8) {
        int2 ed = ep[p];
        acc += __int_as_float(ed.y) * ws[OFF_XT + ed.x * 8 + b];
    }
    acc += __shfl_xor(acc, 8, 64);
    acc += __shfl_xor(acc, 16, 64);
    acc += __shfl_xor(acc, 32, 64);
    if (lane < 8) ws[(m ? OFF_UU : OFF_DD) + r * 8 + lane] = acc;
}

// m=0: y0[r,b] = a0 x + a1 d + a2 u + sum_d v*(sc3 x + sc4 d + sc5 u)[col,b]
// m=1: y1[r,b] =                      sum_u v*(sc6 x + sc7 d + sc8 u)[col,b]
__global__ void k_spmv2(float* __restrict__ ws)
{
    int wid = (blockIdx.x * 256 + threadIdx.x) >> 6;   // 0 .. 16383 (= bucket)
    int lane = threadIdx.x & 63;
    int m = wid >> 13, r = wid & (D - 1);
    const float* sc = ws + OFF_SC;
    const int* cnt = (const int*)ws + IOFF_CNT;
    const int2* edges = (const int2*)((const int*)ws + IOFF_EDGE);
    int deg = cnt[wid];
    const int2* ep = edges + wid * MAXDEG;
    float c0, c1, c2;
    if (m == 0) { c0 = sc[3]; c1 = sc[4]; c2 = sc[5]; }
    else        { c0 = sc[6]; c1 = sc[7]; c2 = sc[8]; }
    int slot = lane >> 3, b = lane & 7;
    float acc = 0.f;
    for (int p = slot; p < deg; p += 8) {
        int2 ed = ep[p];
        int ci = ed.x * 8 + b;
        float h = c0 * ws[OFF_XT + ci] + c1 * ws[OFF_DD + ci] + c2 * ws[OFF_UU + ci];
        acc += __int_as_float(ed.y) * h;
    }
    acc += __shfl_xor(acc, 8, 64);
    acc += __shfl_xor(acc, 16, 64);
    acc += __shfl_xor(acc, 32, 64);
    if (lane < 8) {
        int i = r * 8 + lane;
        if (m == 0) {
            acc += sc[0] * ws[OFF_XT + i] + sc[1] * ws[OFF_DD + i] + sc[2] * ws[OFF_UU + i];
            ws[OFF_Y0 + i] = acc;
        } else {
            ws[OFF_Y1 + i] = acc;
        }
    }
}

// g[b,j] += sum_n (y0+y1)[n,b] * map_w[n,j]   (64 blocks x 128 rows each)
__global__ void k_map(const float* __restrict__ map_w, float* __restrict__ ws)
{
    __shared__ float yl[128 * 8];
    int blk = blockIdx.x, tid = threadIdx.x;
    float* g = ws + OFF_G;
    int base = blk * 128 * 8;
    for (int i = tid; i < 1024; i += 256)
        yl[i] = ws[OFF_Y0 + base + i] + ws[OFF_Y1 + base + i];
    __syncthreads();
    float acc[8] = {0.f, 0.f, 0.f, 0.f, 0.f, 0.f, 0.f, 0.f};
    int nbase = blk * 128;
    #pragma unroll 4
    for (int r = 0; r < 128; r++) {
        float w = map_w[(nbase + r) * HID + tid];
        #pragma unroll
        for (int b = 0; b < 8; b++) acc[b] += yl[r * 8 + b] * w;
    }
    #pragma unroll
    for (int b = 0; b < 8; b++) atomicAdd(&g[b * HID + tid], acc[b]);
}

// s[b,j] = silu(sum_i g[b,i]*o_w1[i,j] + o_b1[j])  (8 blocks x 1024 thr, 4-way split)
__global__ __launch_bounds__(1024) void k_mlp(const float* __restrict__ o_w1,
                                              const float* __restrict__ o_b1,
                                              float* __restrict__ ws)
{
    __shared__ float gs[HID];
    __shared__ float part[4][HID];
    int b = blockIdx.x, tid = threadIdx.x;
    if (tid < HID) gs[tid] = (ws + OFF_G)[b * HID + tid];
    __syncthreads();
    int j = tid & 255, ic = tid >> 8;
    float z = 0.f;
    #pragma unroll 8
    for (int i = ic * 64; i < ic * 64 + 64; i++) z += gs[i] * o_w1[i * HID + j];
    part[ic][j] = z;
    __syncthreads();
    if (tid < HID) {
        float zz = o_b1[tid] + part[0][tid] + part[1][tid] + part[2][tid] + part[3][tid];
        (ws + OFF_S)[b * HID + tid] = zz / (1.f + expf(-zz));
    }
}

// out[b,n] += sum_j s[b,j]*o_w2[j,n]   (grid 32 n-chunks x 4 j-chunks, out pre-biased)
__global__ void k_out(const float* __restrict__ o_w2, const float* __restrict__ ws,
                      float* __restrict__ out)
{
    __shared__ float ssl[8 * 64];
    int nc = blockIdx.x, jc = blockIdx.y, tid = threadIdx.x;
    const float* s = ws + OFF_S;
    for (int i = tid; i < 512; i += 256) {
        int b = i >> 6, jj = i & 63;
        ssl[i] = s[b * HID + jc * 64 + jj];
    }
    __syncthreads();
    int n = nc * 256 + tid;
    float acc[8] = {0.f, 0.f, 0.f, 0.f, 0.f, 0.f, 0.f, 0.f};
    #pragma unroll 4
    for (int jj = 0; jj < 64; jj++) {
        int j = jc * 64 + jj;
        float w = o_w2[j * D + n];
        #pragma unroll
        for (int b = 0; b < 8; b++) acc[b] += ssl[b * 64 + jj] * w;
    }
    #pragma unroll
    for (int b = 0; b < 8; b++) atomicAdd(&out[b * D + n], acc[b]);
}

extern "C" void kernel_launch(void* const* d_in, const int* in_sizes, int n_in,
                              void* d_out, int out_size, void* d_ws, size_t ws_size,
                              hipStream_t stream)
{
    const float* x     = (const float*)d_in[0];
    const float* t     = (const float*)d_in[1];
    const int*   ldi   = (const int*)  d_in[2];
    const float* ldv   = (const float*)d_in[3];
    const int*   lui   = (const int*)  d_in[4];
    const float* luv   = (const float*)d_in[5];
    const float* W1    = (const float*)d_in[6];
    const float* W2    = (const float*)d_in[7];
    const float* t_w1  = (const float*)d_in[8];
    const float* t_b1  = (const float*)d_in[9];
    const float* t_w2  = (const float*)d_in[10];
    const float* t_b2  = (const float*)d_in[11];
    const float* map_w = (const float*)d_in[12];
    const float* map_b = (const float*)d_in[13];
    const float* o_w1  = (const float*)d_in[14];
    const float* o_b1  = (const float*)d_in[15];
    const float* o_w2  = (const float*)d_in[16];
    const float* o_b2  = (const float*)d_in[17];
    float* out = (float*)d_out;
    float* ws  = (float*)d_ws;

    k_front<<<73, 1024, 0, stream>>>(x, t, W1, W2, t_w1, t_b1, t_w2, t_b2,
                                     map_b, o_b2, ws, out);
    k_fill<<<2 * E / 256, 256, 0, stream>>>(ldi, ldv, lui, luv, ws);
    k_spmv1<<<4096, 256, 0, stream>>>(ws);
    k_spmv2<<<4096, 256, 0, stream>>>(ws);
    k_map<<<64, 256, 0, stream>>>(map_w, ws);
    k_mlp<<<8, 1024, 0, stream>>>(o_w1, o_b1, ws);
    k_out<<<dim3(32, 4), 256, 0, stream>>>(o_w2, ws, out);
}